// Round 16
// baseline (383.578 us; speedup 1.0000x reference)
//
#include <hip/hip_runtime.h>
#include <math.h>

#define N_NODES 50000
#define N_EDGES 1600000
#define DIN 16
#define H 256
#define RPB 16
#define LN_EPS 1e-5f
#define FIXS 8388608.0f   // 2^23
#define NB 391            // buckets of 128 dst nodes
#define CAP 5120          // bucket capacity
#define TILEA 4096
#define NTILES 391
#define GRU_COLS 48       // 3 gates x 16 cols per ct step
#define GRU_STR 272       // wbuf col stride in shorts
#define DSTR 264          // dtile row stride in shorts

typedef __attribute__((ext_vector_type(8))) unsigned short u16x8;
typedef __attribute__((ext_vector_type(8))) __bf16 bf16x8;
typedef __attribute__((ext_vector_type(4))) float f32x4;

__device__ inline unsigned short f2bf(float f) {
    unsigned u = __builtin_bit_cast(unsigned, f);
    return (unsigned short)((u + 0x7FFFu + ((u >> 16) & 1u)) >> 16);
}
__device__ inline float bf2f(unsigned short u) {
    return __builtin_bit_cast(float, ((unsigned)u) << 16);
}
__device__ inline float fsig(float x) { return 1.0f / (1.0f + __expf(-x)); }
__device__ inline float ftanh(float x) { return 2.0f / (1.0f + __expf(-2.0f * x)) - 1.0f; }

// ---------------- merged weight prep + xb + bcursor zero ----------------
__global__ void k_wprep(const float* Wih, const float* W2, const float* Wd1, const float* Wd2,
                        const float* x, unsigned short* Wg, unsigned short* W2T,
                        unsigned short* Wd1T, unsigned short* Wd2T, unsigned short* xb,
                        int* bcursor) {
    int idx = blockIdx.x * blockDim.x + threadIdx.x;
    if (idx < 768 * 256) { Wg[idx] = f2bf(Wih[idx]); return; }
    idx -= 768 * 256;
    if (idx < 256 * 256) { int k = idx >> 8, n = idx & 255; W2T[n * 256 + k] = f2bf(W2[idx]); return; }
    idx -= 256 * 256;
    if (idx < 256 * 288) {
        int n = idx / 288, k = idx % 288;
        Wd1T[idx] = (k < 272) ? f2bf(Wd1[k * 256 + n]) : (unsigned short)0;
        return;
    }
    idx -= 256 * 288;
    if (idx < 128 * 256) { int k = idx >> 7, n = idx & 127; Wd2T[n * 256 + k] = f2bf(Wd2[idx]); return; }
    idx -= 128 * 256;
    if (idx < N_NODES * 32) {
        int row = idx >> 5, j = idx & 31;
        xb[idx] = (j < 16) ? f2bf(x[row * DIN + j]) : (unsigned short)0;
        return;
    }
    idx -= N_NODES * 32;
    if (idx < 512) bcursor[idx] = 0;
}

// ---------------- single-pass multisplit into fixed-capacity bucket regions ----------------
// packed u64 = ew(32) << 32 | dstlow7 << 16 | src(16); edge dtype detected inline
__global__ __launch_bounds__(256) void k_msplit(const void* ei, const float* ew,
                                                int* bcursor, unsigned long long* stage) {
    __shared__ int bh[512], bscn[512], cur[512], gbase[512];
    __shared__ int ws4[4];
    __shared__ unsigned long long sdata[TILEA];
    __shared__ unsigned short sbkt[TILEA];
    int t = threadIdx.x;
    long long base = (long long)blockIdx.x * TILEA;
    int nhere = (int)(((long long)N_EDGES - base) < TILEA ? (N_EDGES - base) : TILEA);
    for (int i = t; i < 512; i += 256) bh[i] = 0;
    bool f64;
    {
        const long long* p = (const long long*)ei;
        f64 = true;
        for (int i = 0; i < 8; ++i) { long long v = p[i]; if (v < 0 || v >= N_NODES) f64 = false; }
    }
    __syncthreads();
    unsigned long long vreg[TILEA / 256];
    int breg[TILEA / 256];
#pragma unroll
    for (int k = 0; k < TILEA / 256; ++k) {
        long long e = base + k * 256 + t;
        if (e < N_EDGES) {
            int s, d;
            if (f64) {
                const long long* p = (const long long*)ei;
                s = (int)p[e]; d = (int)p[N_EDGES + e];
            } else {
                const int* p = (const int*)ei;
                s = p[e]; d = p[N_EDGES + e];
            }
            unsigned wbits = __builtin_bit_cast(unsigned, ew[e]);
            vreg[k] = ((unsigned long long)wbits << 32) |
                      ((unsigned long long)(d & 127) << 16) | (unsigned)(s & 0xFFFF);
            breg[k] = d >> 7;
            atomicAdd(&bh[breg[k]], 1);
        } else breg[k] = -1;
    }
    __syncthreads();
    int a0 = bh[2 * t], a1 = bh[2 * t + 1];
    int s = a0 + a1;
    int lane = t & 63, wv = t >> 6;
    int sc = s;
    for (int d = 1; d < 64; d <<= 1) { int u = __shfl_up(sc, d, 64); if (lane >= d) sc += u; }
    if (lane == 63) ws4[wv] = sc;
    __syncthreads();
    int wpre = 0;
    for (int i = 0; i < wv; ++i) wpre += ws4[i];
    int excl = wpre + sc - s;
    bscn[2 * t] = excl;      cur[2 * t] = excl;
    bscn[2 * t + 1] = excl + a0; cur[2 * t + 1] = excl + a0;
    __syncthreads();
    for (int i = t; i < NB; i += 256) {
        int c = bh[i];
        if (c) gbase[i] = atomicAdd(&bcursor[i], c);
    }
    __syncthreads();
#pragma unroll
    for (int k = 0; k < TILEA / 256; ++k) {
        if (breg[k] >= 0) {
            int p = atomicAdd(&cur[breg[k]], 1);
            sdata[p] = vreg[k];
            sbkt[p] = (unsigned short)breg[k];
        }
    }
    __syncthreads();
    for (int i = t; i < nhere; i += 256) {
        int b = sbkt[i];
        stage[(long long)b * CAP + gbase[b] + (i - bscn[b])] = sdata[i];
    }
}

// ---------------- fused: degree/dis + scan -> offs/oend + CSR placement + xpb ----------------
__global__ __launch_bounds__(256) void k_bfin(const unsigned long long* __restrict__ stage,
                                              const int* __restrict__ bcursor,
                                              const float* __restrict__ x,
                                              float* __restrict__ dis,
                                              int* __restrict__ offs, int* __restrict__ oend,
                                              unsigned* __restrict__ csr,
                                              unsigned short* __restrict__ xpb) {
    __shared__ unsigned long long acc[128];
    __shared__ int sc[128];
    __shared__ int cur[128];
    __shared__ float sdis[128];
    int b = blockIdx.x, t = threadIdx.x;
    if (t < 128) acc[t] = 0ULL;
    __syncthreads();
    long long e0 = (long long)b * CAP;
    int n = bcursor[b];
    for (int i = t; i < n; i += 256) {
        unsigned long long v = stage[e0 + i];
        int nl = (int)((v >> 16) & 127);
        float w = __builtin_bit_cast(float, (unsigned)(v >> 32));
        atomicAdd(&acc[nl], (1ULL << 43) | (unsigned long long)llrintf(w * FIXS));
    }
    __syncthreads();
    int mycnt = 0;
    if (t < 128) {
        unsigned long long v = acc[t];
        mycnt = (int)(v >> 43);
        sc[t] = mycnt;
        float dv = rsqrtf((float)(v & ((1ULL << 43) - 1)) * (1.0f / FIXS) + 2.0f);
        sdis[t] = dv;
        int node = (b << 7) + t;
        if (node < N_NODES) dis[node] = dv;
    }
    __syncthreads();
    for (int d = 1; d < 128; d <<= 1) {
        int v = 0;
        if (t < 128 && t >= d) v = sc[t - d];
        __syncthreads();
        if (t < 128 && t >= d) sc[t] += v;
        __syncthreads();
    }
    if (t < 128) {
        int excl = sc[t] - mycnt;
        cur[t] = excl;
        int node = (b << 7) + t;
        if (node < N_NODES) {
            offs[node] = (int)(e0 + excl);
            oend[node] = (int)(e0 + excl + mycnt);
        }
    }
    __syncthreads();
    for (int i = t; i < n; i += 256) {
        unsigned long long v = stage[e0 + i];
        int nl = (int)((v >> 16) & 127);
        int p = atomicAdd(&cur[nl], 1);
        float w = __builtin_bit_cast(float, (unsigned)(v >> 32));
        csr[e0 + p] = ((unsigned)f2bf(w) << 16) | (unsigned)(v & 0xFFFFu);
    }
    // xp = bf16(dis * x) for this bucket's nodes
    for (int i = t; i < 128 * DIN; i += 256) {
        int nl = i >> 4, dd = i & 15;
        int node = (b << 7) + nl;
        if (node < N_NODES) xpb[node * DIN + dd] = f2bf(sdis[nl] * x[node * DIN + dd]);
    }
}

// ---------------- fused layer-1: aggregation (DIN) + GEMM(16->256) + bias + LN + relu + dis-scale ----------------
__global__ __launch_bounds__(256) void k_l1(const unsigned short* __restrict__ xpb,
        const int* __restrict__ offs, const int* __restrict__ oend,
        const unsigned* __restrict__ csr, const float* __restrict__ dis,
        const float* __restrict__ W, const float* __restrict__ bias,
        const float* __restrict__ g, const float* __restrict__ be,
        unsigned short* __restrict__ out) {
    __shared__ float s[RPB][H + 1];
    __shared__ float smu[RPB], srs[RPB];
    int t = threadIdx.x;
    long long rowbase = (long long)blockIdx.x * RPB;
    {
        int r = blockIdx.x * 16 + (t >> 4);
        int dd = t & 15;
        float di = dis[r];
        float xself = bf2f(xpb[(long long)r * DIN + dd]);
        float acc = 0.0f;
        int e0 = offs[r], e1 = oend[r];
        for (int e = e0; e < e1; e += 8) {
            unsigned vv[8];
#pragma unroll
            for (int j = 0; j < 8; ++j) {
                int idx = e + j;
                vv[j] = (idx < e1) ? csr[idx] : (unsigned)r;
            }
            float xx[8];
#pragma unroll
            for (int j = 0; j < 8; ++j) {
                int sidx = (int)(vv[j] & 0xFFFFu);
                xx[j] = bf2f(xpb[(long long)sidx * DIN + dd]);
            }
#pragma unroll
            for (int j = 0; j < 8; ++j) {
                float c = bf2f((unsigned short)(vv[j] >> 16));
                acc = fmaf(c, xx[j], acc);
            }
        }
        s[t >> 4][dd] = di * acc + 2.0f * di * xself;
    }
    __syncthreads();
    float acc2[RPB];
    float bb0 = bias[t];
#pragma unroll
    for (int r = 0; r < RPB; ++r) acc2[r] = bb0;
    for (int k = 0; k < DIN; ++k) {
        float wv = W[k * H + t];
#pragma unroll
        for (int r = 0; r < RPB; ++r) acc2[r] = fmaf(s[r][k], wv, acc2[r]);
    }
    __syncthreads();
#pragma unroll
    for (int r = 0; r < RPB; ++r) s[r][t] = acc2[r];
    __syncthreads();
    int lane = t & 63, wv2 = t >> 6;
    for (int rr = wv2; rr < RPB; rr += 4) {
        float v0 = s[rr][lane], v1 = s[rr][lane + 64], v2 = s[rr][lane + 128], v3 = s[rr][lane + 192];
        float sm = v0 + v1 + v2 + v3;
        float sq = v0 * v0 + v1 * v1 + v2 * v2 + v3 * v3;
        for (int d = 32; d; d >>= 1) {
            sm += __shfl_down(sm, d, 64);
            sq += __shfl_down(sq, d, 64);
        }
        if (lane == 0) {
            float mu = sm * (1.0f / H);
            float var = sq * (1.0f / H) - mu * mu;
            smu[rr] = mu;
            srs[rr] = rsqrtf(var + LN_EPS);
        }
    }
    __syncthreads();
    float gg = g[t], bb = be[t];
#pragma unroll
    for (int r = 0; r < RPB; ++r) {
        float h = fmaxf((acc2[r] - smu[r]) * srs[r] * gg + bb, 0.0f);
        out[(rowbase + r) * H + t] = f2bf(h * dis[rowbase + r]);
    }
}

// ---------------- SpMM in H space: full-row gather, 16-deep MLP ----------------
__global__ __launch_bounds__(256) void k_spmm(const unsigned short* __restrict__ hin,
                                              unsigned short* __restrict__ hout,
                                              const int* __restrict__ offs,
                                              const int* __restrict__ oend,
                                              const unsigned* __restrict__ csr,
                                              const float* __restrict__ dis) {
    int t = threadIdx.x;
    int wv = t >> 6, lane = t & 63;
    int row = blockIdx.x * 4 + wv;
    const ushort4* h4 = (const ushort4*)hin;
    float di = dis[row];
    ushort4 vs = h4[(long long)row * 64 + lane];
    float a0 = 0.f, a1 = 0.f, a2 = 0.f, a3 = 0.f;
    int e0 = offs[row], e1 = oend[row];
    for (int e = e0; e < e1; e += 16) {
        unsigned vv[16];
#pragma unroll
        for (int j = 0; j < 16; ++j) {
            int idx = e + j;
            vv[j] = (idx < e1) ? csr[idx] : (unsigned)row;
        }
        ushort4 uu[16];
#pragma unroll
        for (int j = 0; j < 16; ++j) {
            int s = (int)(vv[j] & 0xFFFFu);
            uu[j] = h4[(long long)s * 64 + lane];
        }
#pragma unroll
        for (int j = 0; j < 16; ++j) {
            float c = bf2f((unsigned short)(vv[j] >> 16));
            a0 = fmaf(c, bf2f(uu[j].x), a0);
            a1 = fmaf(c, bf2f(uu[j].y), a1);
            a2 = fmaf(c, bf2f(uu[j].z), a2);
            a3 = fmaf(c, bf2f(uu[j].w), a3);
        }
    }
    ushort4 o;
    o.x = f2bf(di * a0 + 2.0f * di * bf2f(vs.x));
    o.y = f2bf(di * a1 + 2.0f * di * bf2f(vs.y));
    o.z = f2bf(di * a2 + 2.0f * di * bf2f(vs.z));
    o.w = f2bf(di * a3 + 2.0f * di * bf2f(vs.w));
    ((ushort4*)hout)[(long long)row * 64 + lane] = o;
}

// ---------------- fused tail: LN(mfma) -> GRU(dbuf via dtile-alias, deferred out) -> decoder ----------------
// frag layout (16x16x32 bf16): A lane l: row l&15, k=8*(l>>4)+j ; B lane l: col l&15, same k ;
// D lane l: col l&15, row 4*(l>>4)+reg
__global__ __launch_bounds__(256) void k_lgd(
        const unsigned short* __restrict__ Bbf,
        const unsigned short* __restrict__ W2T, const float* __restrict__ b2,
        const float* __restrict__ g2, const float* __restrict__ be2,
        const unsigned short* __restrict__ Wg, const float* __restrict__ bih,
        const float* __restrict__ bhh,
        const unsigned short* __restrict__ W1T, const float* __restrict__ bd1,
        const unsigned short* __restrict__ Wd2T, const float* __restrict__ bd2,
        const float* __restrict__ Wd3, const float* __restrict__ bd3,
        const unsigned short* __restrict__ xb, float* __restrict__ out) {
    __shared__ unsigned short wbuf[GRU_COLS * GRU_STR];   // 26.1 KB (buffer 0)
    __shared__ unsigned short dtile[64][DSTR];            // 33.8 KB; aliased as buffer 1 in phase B
    int t = threadIdx.x;
    int wv = t >> 6, l = t & 63;
    int lr = l & 15, lg = l >> 4;
    int rb = blockIdx.x * 64 + wv * 16;
    int arow = rb + lr; if (arow >= N_NODES) arow = N_NODES - 1;

    // ---- phase A: h2 = LN(Bbf @ W2 + b2) -> dtile ----
    {
        bf16x8 af[8];
        const unsigned short* ap = Bbf + (long long)arow * H + lg * 8;
#pragma unroll
        for (int ks = 0; ks < 8; ++ks) af[ks] = __builtin_bit_cast(bf16x8, *(const u16x8*)(ap + ks * 32));
        f32x4 acc[16];
#pragma unroll
        for (int ct = 0; ct < 16; ++ct) acc[ct] = (f32x4){0.f, 0.f, 0.f, 0.f};
        for (int ct = 0; ct < 16; ++ct) {
            const unsigned short* wr = W2T + (ct * 16 + lr) * H + lg * 8;
#pragma unroll
            for (int ks = 0; ks < 8; ++ks) {
                bf16x8 bfv = __builtin_bit_cast(bf16x8, *(const u16x8*)(wr + ks * 32));
                acc[ct] = __builtin_amdgcn_mfma_f32_16x16x32_bf16(af[ks], bfv, acc[ct], 0, 0, 0);
            }
        }
#pragma unroll
        for (int ct = 0; ct < 16; ++ct) {
            float bb = b2[ct * 16 + lr];
#pragma unroll
            for (int q = 0; q < 4; ++q) acc[ct][q] += bb;
        }
        float mean[4], rstd[4];
#pragma unroll
        for (int q = 0; q < 4; ++q) {
            float s = 0.f, s2 = 0.f;
#pragma unroll
            for (int ct = 0; ct < 16; ++ct) { float v = acc[ct][q]; s += v; s2 += v * v; }
#pragma unroll
            for (int m = 1; m < 16; m <<= 1) { s += __shfl_xor(s, m, 64); s2 += __shfl_xor(s2, m, 64); }
            float mu = s * (1.0f / H);
            mean[q] = mu;
            rstd[q] = rsqrtf(s2 * (1.0f / H) - mu * mu + LN_EPS);
        }
#pragma unroll
        for (int ct = 0; ct < 16; ++ct) {
            int col = ct * 16 + lr;
            float gg = g2[col], bb = be2[col];
#pragma unroll
            for (int q = 0; q < 4; ++q) {
                float nv = (acc[ct][q] - mean[q]) * rstd[q] * gg + bb;
                dtile[wv * 16 + lg * 4 + q][col] = f2bf(nv);
            }
        }
    }
    __syncthreads();

    // ---- phase B: GRU; 48-col double-buffer (wbuf + dtile-alias), deferred outputs ----
    {
        bf16x8 ah[8];
        const unsigned short* lp = &dtile[wv * 16 + lr][0] + lg * 8;
#pragma unroll
        for (int ks = 0; ks < 8; ++ks) ah[ks] = __builtin_bit_cast(bf16x8, *(const u16x8*)(lp + ks * 32));
        unsigned short* wbuf0 = wbuf;
        unsigned short* wbuf1 = &dtile[0][0];     // dtile storage dead until phase-B end
        u16x8 pre[6];
        auto issue = [&](int ct) {
#pragma unroll
            for (int j = 0; j < 6; ++j) {
                int i = t + j * 256;          // 0..1535
                int col = i >> 5;             // 0..47 (gate*16 + c)
                int off = (i & 31) * 8;       // shorts
                int gate = col >> 4, c = col & 15;
                pre[j] = *(const u16x8*)(Wg + ((gate * 256 + ct * 16 + c) * 256 + off));
            }
        };
        auto commit = [&](unsigned short* dst) {
#pragma unroll
            for (int j = 0; j < 6; ++j) {
                int i = t + j * 256;
                int col = i >> 5;
                int off = (i & 31) * 8;
                *(u16x8*)(&dst[col * GRU_STR + off]) = pre[j];
            }
        };
        issue(0);
        commit(wbuf0);     // safe: wbuf0 storage untouched by ah loads
        __syncthreads();   // ah loads done by all waves; wbuf0 ready
        unsigned outw[16][2];
        for (int ct = 0; ct < 16; ++ct) {
            if (ct < 15) issue(ct + 1);     // loads in flight during MFMAs
            const unsigned short* cbuf = (ct & 1) ? wbuf1 : wbuf0;
            const unsigned short* base = cbuf + lr * GRU_STR + lg * 8;
            f32x4 aR = (f32x4){0.f, 0.f, 0.f, 0.f};
            f32x4 aZ = aR, aN = aR;
#pragma unroll
            for (int ks = 0; ks < 8; ++ks) {
                bf16x8 b0 = __builtin_bit_cast(bf16x8, *(const u16x8*)(base + ks * 32));
                bf16x8 b1 = __builtin_bit_cast(bf16x8, *(const u16x8*)(base + 16 * GRU_STR + ks * 32));
                bf16x8 b2v = __builtin_bit_cast(bf16x8, *(const u16x8*)(base + 32 * GRU_STR + ks * 32));
                aR = __builtin_amdgcn_mfma_f32_16x16x32_bf16(ah[ks], b0, aR, 0, 0, 0);
                aZ = __builtin_amdgcn_mfma_f32_16x16x32_bf16(ah[ks], b1, aZ, 0, 0, 0);
                aN = __builtin_amdgcn_mfma_f32_16x16x32_bf16(ah[ks], b2v, aN, 0, 0, 0);
            }
            int col = ct * 16 + lr;
            float bR = bih[col] + bhh[col];
            float bZ = bih[col + 256] + bhh[col + 256];
            float bN = bih[col + 512];
            float hN = bhh[col + 512];
            unsigned w0, w1;
            {
                float r0 = fsig(aR[0] + bR), z0 = fsig(aZ[0] + bZ);
                float n0 = ftanh(aN[0] + bN + r0 * hN);
                float r1 = fsig(aR[1] + bR), z1 = fsig(aZ[1] + bZ);
                float n1 = ftanh(aN[1] + bN + r1 * hN);
                w0 = (unsigned)f2bf((1.0f - z0) * n0) | ((unsigned)f2bf((1.0f - z1) * n1) << 16);
                float r2 = fsig(aR[2] + bR), z2 = fsig(aZ[2] + bZ);
                float n2 = ftanh(aN[2] + bN + r2 * hN);
                float r3 = fsig(aR[3] + bR), z3 = fsig(aZ[3] + bZ);
                float n3 = ftanh(aN[3] + bN + r3 * hN);
                w1 = (unsigned)f2bf((1.0f - z2) * n2) | ((unsigned)f2bf((1.0f - z3) * n3) << 16);
            }
            outw[ct][0] = w0;
            outw[ct][1] = w1;
            if (ct < 15) commit((ct & 1) ? wbuf0 : wbuf1);   // next buffer
            __syncthreads();
        }
        // deferred GRU outputs -> dtile (own-wave rows; all buf readers retired by final barrier)
#pragma unroll
        for (int ct = 0; ct < 16; ++ct) {
            int col = ct * 16 + lr;
            dtile[wv * 16 + lg * 4 + 0][col] = (unsigned short)(outw[ct][0] & 0xFFFFu);
            dtile[wv * 16 + lg * 4 + 1][col] = (unsigned short)(outw[ct][0] >> 16);
            dtile[wv * 16 + lg * 4 + 2][col] = (unsigned short)(outw[ct][1] & 0xFFFFu);
            dtile[wv * 16 + lg * 4 + 3][col] = (unsigned short)(outw[ct][1] >> 16);
        }
    }
    __syncthreads();

    // ---- phase C: d1 = relu([temporal, x] @ Wd1 + bd1) -> dtile ----
    {
        bf16x8 ad[9];
        const unsigned short* lp = &dtile[wv * 16 + lr][0] + lg * 8;
#pragma unroll
        for (int ks = 0; ks < 8; ++ks) ad[ks] = __builtin_bit_cast(bf16x8, *(const u16x8*)(lp + ks * 32));
        ad[8] = __builtin_bit_cast(bf16x8, *(const u16x8*)(xb + (long long)arow * 32 + lg * 8));
        f32x4 acc[16];
#pragma unroll
        for (int ct = 0; ct < 16; ++ct) acc[ct] = (f32x4){0.f, 0.f, 0.f, 0.f};
        for (int ct = 0; ct < 16; ++ct) {
            const unsigned short* wr = W1T + (ct * 16 + lr) * 288 + lg * 8;
#pragma unroll
            for (int ks = 0; ks < 9; ++ks) {
                bf16x8 bfv = __builtin_bit_cast(bf16x8, *(const u16x8*)(wr + ks * 32));
                acc[ct] = __builtin_amdgcn_mfma_f32_16x16x32_bf16(ad[ks], bfv, acc[ct], 0, 0, 0);
            }
        }
#pragma unroll
        for (int ct = 0; ct < 16; ++ct) {
            float bb = bd1[ct * 16 + lr];
#pragma unroll
            for (int q = 0; q < 4; ++q) {
                float v = fmaxf(acc[ct][q] + bb, 0.0f);
                dtile[wv * 16 + lg * 4 + q][ct * 16 + lr] = f2bf(v);
            }
        }
    }
    __syncthreads();

    // ---- phase D: d2 = relu(d1 @ Wd2 + bd2); pred = clip(d2 @ Wd3 + bd3) ----
    bf16x8 af[8];
    const unsigned short* lp = &dtile[wv * 16 + lr][0] + lg * 8;
#pragma unroll
    for (int ks = 0; ks < 8; ++ks) af[ks] = __builtin_bit_cast(bf16x8, *(const u16x8*)(lp + ks * 32));
    f32x4 acc[8];
#pragma unroll
    for (int ct = 0; ct < 8; ++ct) acc[ct] = (f32x4){0.f, 0.f, 0.f, 0.f};
    for (int ct = 0; ct < 8; ++ct) {
        const unsigned short* wr = Wd2T + (ct * 16 + lr) * H + lg * 8;
#pragma unroll
        for (int ks = 0; ks < 8; ++ks) {
            bf16x8 bfv = __builtin_bit_cast(bf16x8, *(const u16x8*)(wr + ks * 32));
            acc[ct] = __builtin_amdgcn_mfma_f32_16x16x32_bf16(af[ks], bfv, acc[ct], 0, 0, 0);
        }
    }
    float p0[4] = {0.f, 0.f, 0.f, 0.f}, p1[4] = {0.f, 0.f, 0.f, 0.f};
#pragma unroll
    for (int ct = 0; ct < 8; ++ct) {
        int col = ct * 16 + lr;
        float bb = bd2[col];
        float2 w3 = *(const float2*)(Wd3 + col * 2);
#pragma unroll
        for (int q = 0; q < 4; ++q) {
            float v = fmaxf(acc[ct][q] + bb, 0.0f);
            p0[q] = fmaf(v, w3.x, p0[q]);
            p1[q] = fmaf(v, w3.y, p1[q]);
        }
    }
#pragma unroll
    for (int q = 0; q < 4; ++q) {
#pragma unroll
        for (int m = 1; m < 16; m <<= 1) {
            p0[q] += __shfl_xor(p0[q], m, 64);
            p1[q] += __shfl_xor(p1[q], m, 64);
        }
    }
    if (lr == 0) {
#pragma unroll
        for (int q = 0; q < 4; ++q) {
            int row = rb + lg * 4 + q;
            if (row < N_NODES) {
                float a = fminf(fmaxf(p0[q] + bd3[0], -5.0f), 5.0f);
                float b = fminf(fmaxf(p1[q] + bd3[1], -5.0f), 5.0f);
                out[(long long)row * 2] = a;
                out[(long long)row * 2 + 1] = b;
            }
        }
    }
}

extern "C" void kernel_launch(void* const* d_in, const int* in_sizes, int n_in,
                              void* d_out, int out_size, void* d_ws, size_t ws_size,
                              hipStream_t stream) {
    const float* x   = (const float*)d_in[0];
    const void*  ei  = d_in[1];
    const float* ew  = (const float*)d_in[2];
    const float* W1  = (const float*)d_in[3];
    const float* b1  = (const float*)d_in[4];
    const float* g1  = (const float*)d_in[5];
    const float* be1 = (const float*)d_in[6];
    const float* W2  = (const float*)d_in[7];
    const float* b2  = (const float*)d_in[8];
    const float* g2  = (const float*)d_in[9];
    const float* be2 = (const float*)d_in[10];
    const float* Wih = (const float*)d_in[11];
    const float* bih = (const float*)d_in[13];
    const float* bhh = (const float*)d_in[14];
    const float* Wd1 = (const float*)d_in[15];
    const float* bd1 = (const float*)d_in[16];
    const float* Wd2 = (const float*)d_in[17];
    const float* bd2 = (const float*)d_in[18];
    const float* Wd3 = (const float*)d_in[19];
    const float* bd3 = (const float*)d_in[20];
    float* out = (float*)d_out;

    char* w = (char*)d_ws;
    size_t pos = 0;
    auto carve = [&](size_t bytes) -> void* {
        void* p = w + pos;
        pos += (bytes + 255) & ~(size_t)255;
        return p;
    };
    int*   bcursor = (int*)carve(sizeof(int) * 512);
    float* dis     = (float*)carve(sizeof(float) * N_NODES);
    int*   offs    = (int*)carve(sizeof(int) * N_NODES);
    int*   oend    = (int*)carve(sizeof(int) * N_NODES);
    unsigned long long* stage = (unsigned long long*)carve(8 * (size_t)NB * CAP);
    unsigned* csr = (unsigned*)carve(4 * (size_t)NB * CAP);
    unsigned short* xpb  = (unsigned short*)carve(2 * (size_t)N_NODES * DIN);
    unsigned short* xb   = (unsigned short*)carve(2 * (size_t)N_NODES * 32);
    unsigned short* Wg   = (unsigned short*)carve(2 * 768 * 256);
    unsigned short* W2T  = (unsigned short*)carve(2 * 256 * 256);
    unsigned short* Wd1T = (unsigned short*)carve(2 * 256 * 288);
    unsigned short* Wd2T = (unsigned short*)carve(2 * 128 * 256);
    unsigned short* Abf = (unsigned short*)carve(2 * (size_t)N_NODES * H);  // h1p bf16
    unsigned short* Bbf = (unsigned short*)carve(2 * (size_t)N_NODES * H);  // agg2 bf16
    (void)pos; (void)ws_size; (void)in_sizes; (void)n_in; (void)out_size;

    int nbm = (N_NODES + 63) / 64;        // 782
    int nwp = (768 * 256 + 256 * 256 + 256 * 288 + 128 * 256 + N_NODES * 32 + 512 + 255) / 256;

    k_wprep<<<nwp, 256, 0, stream>>>(Wih, W2, Wd1, Wd2, x, Wg, W2T, Wd1T, Wd2T, xb, bcursor);
    k_msplit<<<NTILES, 256, 0, stream>>>(ei, ew, bcursor, stage);
    k_bfin<<<NB, 256, 0, stream>>>(stage, bcursor, x, dis, offs, oend, csr, xpb);
    k_l1<<<N_NODES / RPB, 256, 0, stream>>>(xpb, offs, oend, csr, dis, W1, b1, g1, be1, Abf);
    k_spmm<<<N_NODES / 4, 256, 0, stream>>>(Abf, Bbf, offs, oend, csr, dis);
    k_lgd<<<nbm, 256, 0, stream>>>(Bbf, W2T, b2, g2, be2, Wg, bih, bhh,
                                   Wd1T, bd1, Wd2T, bd2, Wd3, bd3, xb, out);
}

// Round 17
// 353.571 us; speedup vs baseline: 1.0849x; 1.0849x over previous
//
#include <hip/hip_runtime.h>
#include <math.h>

#define N_NODES 50000
#define N_EDGES 1600000
#define DIN 16
#define H 256
#define RPB 16
#define LN_EPS 1e-5f
#define FIXS 8388608.0f   // 2^23
#define NB 391            // buckets of 128 dst nodes
#define CAP 5120          // bucket capacity
#define TILEA 4096
#define NTILES 391
#define GRU_COLS 48       // 3 gates x 16 cols per ct step
#define GRU_STR 272       // wbuf col stride in shorts
#define DSTR 264          // dtile row stride in shorts

typedef __attribute__((ext_vector_type(8))) unsigned short u16x8;
typedef __attribute__((ext_vector_type(8))) __bf16 bf16x8;
typedef __attribute__((ext_vector_type(4))) float f32x4;

__device__ inline unsigned short f2bf(float f) {
    unsigned u = __builtin_bit_cast(unsigned, f);
    return (unsigned short)((u + 0x7FFFu + ((u >> 16) & 1u)) >> 16);
}
__device__ inline float bf2f(unsigned short u) {
    return __builtin_bit_cast(float, ((unsigned)u) << 16);
}
__device__ inline float fsig(float x) { return 1.0f / (1.0f + __expf(-x)); }
__device__ inline float ftanh(float x) { return 2.0f / (1.0f + __expf(-2.0f * x)) - 1.0f; }

// ---------------- merged weight prep + xb + bcursor zero ----------------
__global__ void k_wprep(const float* Wih, const float* W2, const float* Wd1, const float* Wd2,
                        const float* x, unsigned short* Wg, unsigned short* W2T,
                        unsigned short* Wd1T, unsigned short* Wd2T, unsigned short* xb,
                        int* bcursor) {
    int idx = blockIdx.x * blockDim.x + threadIdx.x;
    if (idx < 768 * 256) { Wg[idx] = f2bf(Wih[idx]); return; }
    idx -= 768 * 256;
    if (idx < 256 * 256) { int k = idx >> 8, n = idx & 255; W2T[n * 256 + k] = f2bf(W2[idx]); return; }
    idx -= 256 * 256;
    if (idx < 256 * 288) {
        int n = idx / 288, k = idx % 288;
        Wd1T[idx] = (k < 272) ? f2bf(Wd1[k * 256 + n]) : (unsigned short)0;
        return;
    }
    idx -= 256 * 288;
    if (idx < 128 * 256) { int k = idx >> 7, n = idx & 127; Wd2T[n * 256 + k] = f2bf(Wd2[idx]); return; }
    idx -= 128 * 256;
    if (idx < N_NODES * 32) {
        int row = idx >> 5, j = idx & 31;
        xb[idx] = (j < 16) ? f2bf(x[row * DIN + j]) : (unsigned short)0;
        return;
    }
    idx -= N_NODES * 32;
    if (idx < 512) bcursor[idx] = 0;
}

// ---------------- single-pass multisplit into fixed-capacity bucket regions ----------------
// packed u64 = ew(32) << 32 | dstlow7 << 16 | src(16); edge dtype detected inline
__global__ __launch_bounds__(256) void k_msplit(const void* ei, const float* ew,
                                                int* bcursor, unsigned long long* stage) {
    __shared__ int bh[512], bscn[512], cur[512], gbase[512];
    __shared__ int ws4[4];
    __shared__ unsigned long long sdata[TILEA];
    __shared__ unsigned short sbkt[TILEA];
    int t = threadIdx.x;
    long long base = (long long)blockIdx.x * TILEA;
    int nhere = (int)(((long long)N_EDGES - base) < TILEA ? (N_EDGES - base) : TILEA);
    for (int i = t; i < 512; i += 256) bh[i] = 0;
    bool f64;
    {
        const long long* p = (const long long*)ei;
        f64 = true;
        for (int i = 0; i < 8; ++i) { long long v = p[i]; if (v < 0 || v >= N_NODES) f64 = false; }
    }
    __syncthreads();
    unsigned long long vreg[TILEA / 256];
    int breg[TILEA / 256];
#pragma unroll
    for (int k = 0; k < TILEA / 256; ++k) {
        long long e = base + k * 256 + t;
        if (e < N_EDGES) {
            int s, d;
            if (f64) {
                const long long* p = (const long long*)ei;
                s = (int)p[e]; d = (int)p[N_EDGES + e];
            } else {
                const int* p = (const int*)ei;
                s = p[e]; d = p[N_EDGES + e];
            }
            unsigned wbits = __builtin_bit_cast(unsigned, ew[e]);
            vreg[k] = ((unsigned long long)wbits << 32) |
                      ((unsigned long long)(d & 127) << 16) | (unsigned)(s & 0xFFFF);
            breg[k] = d >> 7;
            atomicAdd(&bh[breg[k]], 1);
        } else breg[k] = -1;
    }
    __syncthreads();
    int a0 = bh[2 * t], a1 = bh[2 * t + 1];
    int s = a0 + a1;
    int lane = t & 63, wv = t >> 6;
    int sc = s;
    for (int d = 1; d < 64; d <<= 1) { int u = __shfl_up(sc, d, 64); if (lane >= d) sc += u; }
    if (lane == 63) ws4[wv] = sc;
    __syncthreads();
    int wpre = 0;
    for (int i = 0; i < wv; ++i) wpre += ws4[i];
    int excl = wpre + sc - s;
    bscn[2 * t] = excl;      cur[2 * t] = excl;
    bscn[2 * t + 1] = excl + a0; cur[2 * t + 1] = excl + a0;
    __syncthreads();
    for (int i = t; i < NB; i += 256) {
        int c = bh[i];
        if (c) gbase[i] = atomicAdd(&bcursor[i], c);
    }
    __syncthreads();
#pragma unroll
    for (int k = 0; k < TILEA / 256; ++k) {
        if (breg[k] >= 0) {
            int p = atomicAdd(&cur[breg[k]], 1);
            sdata[p] = vreg[k];
            sbkt[p] = (unsigned short)breg[k];
        }
    }
    __syncthreads();
    for (int i = t; i < nhere; i += 256) {
        int b = sbkt[i];
        stage[(long long)b * CAP + gbase[b] + (i - bscn[b])] = sdata[i];
    }
}

// ---------------- fused: degree/dis + scan -> offs/oend + CSR placement + xpb ----------------
__global__ __launch_bounds__(256) void k_bfin(const unsigned long long* __restrict__ stage,
                                              const int* __restrict__ bcursor,
                                              const float* __restrict__ x,
                                              float* __restrict__ dis,
                                              int* __restrict__ offs, int* __restrict__ oend,
                                              unsigned* __restrict__ csr,
                                              unsigned short* __restrict__ xpb) {
    __shared__ unsigned long long acc[128];
    __shared__ int sc[128];
    __shared__ int cur[128];
    __shared__ float sdis[128];
    int b = blockIdx.x, t = threadIdx.x;
    if (t < 128) acc[t] = 0ULL;
    __syncthreads();
    long long e0 = (long long)b * CAP;
    int n = bcursor[b];
    for (int i = t; i < n; i += 256) {
        unsigned long long v = stage[e0 + i];
        int nl = (int)((v >> 16) & 127);
        float w = __builtin_bit_cast(float, (unsigned)(v >> 32));
        atomicAdd(&acc[nl], (1ULL << 43) | (unsigned long long)llrintf(w * FIXS));
    }
    __syncthreads();
    int mycnt = 0;
    if (t < 128) {
        unsigned long long v = acc[t];
        mycnt = (int)(v >> 43);
        sc[t] = mycnt;
        float dv = rsqrtf((float)(v & ((1ULL << 43) - 1)) * (1.0f / FIXS) + 2.0f);
        sdis[t] = dv;
        int node = (b << 7) + t;
        if (node < N_NODES) dis[node] = dv;
    }
    __syncthreads();
    for (int d = 1; d < 128; d <<= 1) {
        int v = 0;
        if (t < 128 && t >= d) v = sc[t - d];
        __syncthreads();
        if (t < 128 && t >= d) sc[t] += v;
        __syncthreads();
    }
    if (t < 128) {
        int excl = sc[t] - mycnt;
        cur[t] = excl;
        int node = (b << 7) + t;
        if (node < N_NODES) {
            offs[node] = (int)(e0 + excl);
            oend[node] = (int)(e0 + excl + mycnt);
        }
    }
    __syncthreads();
    for (int i = t; i < n; i += 256) {
        unsigned long long v = stage[e0 + i];
        int nl = (int)((v >> 16) & 127);
        int p = atomicAdd(&cur[nl], 1);
        float w = __builtin_bit_cast(float, (unsigned)(v >> 32));
        csr[e0 + p] = ((unsigned)f2bf(w) << 16) | (unsigned)(v & 0xFFFFu);
    }
    // xp = bf16(dis * x) for this bucket's nodes
    for (int i = t; i < 128 * DIN; i += 256) {
        int nl = i >> 4, dd = i & 15;
        int node = (b << 7) + nl;
        if (node < N_NODES) xpb[node * DIN + dd] = f2bf(sdis[nl] * x[node * DIN + dd]);
    }
}

// ---------------- fused layer-1: aggregation (DIN) + GEMM(16->256) + bias + LN + relu + dis-scale ----------------
__global__ __launch_bounds__(256) void k_l1(const unsigned short* __restrict__ xpb,
        const int* __restrict__ offs, const int* __restrict__ oend,
        const unsigned* __restrict__ csr, const float* __restrict__ dis,
        const float* __restrict__ W, const float* __restrict__ bias,
        const float* __restrict__ g, const float* __restrict__ be,
        unsigned short* __restrict__ out) {
    __shared__ float s[RPB][H + 1];
    __shared__ float smu[RPB], srs[RPB];
    int t = threadIdx.x;
    long long rowbase = (long long)blockIdx.x * RPB;
    {
        int r = blockIdx.x * 16 + (t >> 4);
        int dd = t & 15;
        float di = dis[r];
        float xself = bf2f(xpb[(long long)r * DIN + dd]);
        float acc = 0.0f;
        int e0 = offs[r], e1 = oend[r];
        for (int e = e0; e < e1; e += 8) {
            unsigned vv[8];
#pragma unroll
            for (int j = 0; j < 8; ++j) {
                int idx = e + j;
                vv[j] = (idx < e1) ? csr[idx] : (unsigned)r;
            }
            float xx[8];
#pragma unroll
            for (int j = 0; j < 8; ++j) {
                int sidx = (int)(vv[j] & 0xFFFFu);
                xx[j] = bf2f(xpb[(long long)sidx * DIN + dd]);
            }
#pragma unroll
            for (int j = 0; j < 8; ++j) {
                float c = bf2f((unsigned short)(vv[j] >> 16));
                acc = fmaf(c, xx[j], acc);
            }
        }
        s[t >> 4][dd] = di * acc + 2.0f * di * xself;
    }
    __syncthreads();
    float acc2[RPB];
    float bb0 = bias[t];
#pragma unroll
    for (int r = 0; r < RPB; ++r) acc2[r] = bb0;
    for (int k = 0; k < DIN; ++k) {
        float wv = W[k * H + t];
#pragma unroll
        for (int r = 0; r < RPB; ++r) acc2[r] = fmaf(s[r][k], wv, acc2[r]);
    }
    __syncthreads();
#pragma unroll
    for (int r = 0; r < RPB; ++r) s[r][t] = acc2[r];
    __syncthreads();
    int lane = t & 63, wv2 = t >> 6;
    for (int rr = wv2; rr < RPB; rr += 4) {
        float v0 = s[rr][lane], v1 = s[rr][lane + 64], v2 = s[rr][lane + 128], v3 = s[rr][lane + 192];
        float sm = v0 + v1 + v2 + v3;
        float sq = v0 * v0 + v1 * v1 + v2 * v2 + v3 * v3;
        for (int d = 32; d; d >>= 1) {
            sm += __shfl_down(sm, d, 64);
            sq += __shfl_down(sq, d, 64);
        }
        if (lane == 0) {
            float mu = sm * (1.0f / H);
            float var = sq * (1.0f / H) - mu * mu;
            smu[rr] = mu;
            srs[rr] = rsqrtf(var + LN_EPS);
        }
    }
    __syncthreads();
    float gg = g[t], bb = be[t];
#pragma unroll
    for (int r = 0; r < RPB; ++r) {
        float h = fmaxf((acc2[r] - smu[r]) * srs[r] * gg + bb, 0.0f);
        out[(rowbase + r) * H + t] = f2bf(h * dis[rowbase + r]);
    }
}

// ---------------- SpMM in H space: full-row gather, 16-deep MLP ----------------
__global__ __launch_bounds__(256) void k_spmm(const unsigned short* __restrict__ hin,
                                              unsigned short* __restrict__ hout,
                                              const int* __restrict__ offs,
                                              const int* __restrict__ oend,
                                              const unsigned* __restrict__ csr,
                                              const float* __restrict__ dis) {
    int t = threadIdx.x;
    int wv = t >> 6, lane = t & 63;
    int row = blockIdx.x * 4 + wv;
    const ushort4* h4 = (const ushort4*)hin;
    float di = dis[row];
    ushort4 vs = h4[(long long)row * 64 + lane];
    float a0 = 0.f, a1 = 0.f, a2 = 0.f, a3 = 0.f;
    int e0 = offs[row], e1 = oend[row];
    for (int e = e0; e < e1; e += 16) {
        unsigned vv[16];
#pragma unroll
        for (int j = 0; j < 16; ++j) {
            int idx = e + j;
            vv[j] = (idx < e1) ? csr[idx] : (unsigned)row;
        }
        ushort4 uu[16];
#pragma unroll
        for (int j = 0; j < 16; ++j) {
            int s = (int)(vv[j] & 0xFFFFu);
            uu[j] = h4[(long long)s * 64 + lane];
        }
#pragma unroll
        for (int j = 0; j < 16; ++j) {
            float c = bf2f((unsigned short)(vv[j] >> 16));
            a0 = fmaf(c, bf2f(uu[j].x), a0);
            a1 = fmaf(c, bf2f(uu[j].y), a1);
            a2 = fmaf(c, bf2f(uu[j].z), a2);
            a3 = fmaf(c, bf2f(uu[j].w), a3);
        }
    }
    ushort4 o;
    o.x = f2bf(di * a0 + 2.0f * di * bf2f(vs.x));
    o.y = f2bf(di * a1 + 2.0f * di * bf2f(vs.y));
    o.z = f2bf(di * a2 + 2.0f * di * bf2f(vs.z));
    o.w = f2bf(di * a3 + 2.0f * di * bf2f(vs.w));
    ((ushort4*)hout)[(long long)row * 64 + lane] = o;
}

// ---------------- fused tail: LN(mfma) -> GRU(48-col LDS tile, reg-prefetch) -> decoder ----------------
// frag layout (16x16x32 bf16): A lane l: row l&15, k=8*(l>>4)+j ; B lane l: col l&15, same k ;
// D lane l: col l&15, row 4*(l>>4)+reg
__global__ __launch_bounds__(256) void k_lgd(
        const unsigned short* __restrict__ Bbf,
        const unsigned short* __restrict__ W2T, const float* __restrict__ b2,
        const float* __restrict__ g2, const float* __restrict__ be2,
        const unsigned short* __restrict__ Wg, const float* __restrict__ bih,
        const float* __restrict__ bhh,
        const unsigned short* __restrict__ W1T, const float* __restrict__ bd1,
        const unsigned short* __restrict__ Wd2T, const float* __restrict__ bd2,
        const float* __restrict__ Wd3, const float* __restrict__ bd3,
        const unsigned short* __restrict__ xb, float* __restrict__ out) {
    __shared__ unsigned short wbuf[GRU_COLS * GRU_STR];   // 26.1 KB
    __shared__ unsigned short dtile[64][DSTR];            // 33.8 KB (total 59.9 -> 2 blocks/CU)
    int t = threadIdx.x;
    int wv = t >> 6, l = t & 63;
    int lr = l & 15, lg = l >> 4;
    int rb = blockIdx.x * 64 + wv * 16;
    int arow = rb + lr; if (arow >= N_NODES) arow = N_NODES - 1;

    // ---- phase A: h2 = LN(Bbf @ W2 + b2) -> dtile ----
    {
        bf16x8 af[8];
        const unsigned short* ap = Bbf + (long long)arow * H + lg * 8;
#pragma unroll
        for (int ks = 0; ks < 8; ++ks) af[ks] = __builtin_bit_cast(bf16x8, *(const u16x8*)(ap + ks * 32));
        f32x4 acc[16];
#pragma unroll
        for (int ct = 0; ct < 16; ++ct) acc[ct] = (f32x4){0.f, 0.f, 0.f, 0.f};
        for (int ct = 0; ct < 16; ++ct) {
            const unsigned short* wr = W2T + (ct * 16 + lr) * H + lg * 8;
#pragma unroll
            for (int ks = 0; ks < 8; ++ks) {
                bf16x8 bfv = __builtin_bit_cast(bf16x8, *(const u16x8*)(wr + ks * 32));
                acc[ct] = __builtin_amdgcn_mfma_f32_16x16x32_bf16(af[ks], bfv, acc[ct], 0, 0, 0);
            }
        }
#pragma unroll
        for (int ct = 0; ct < 16; ++ct) {
            float bb = b2[ct * 16 + lr];
#pragma unroll
            for (int q = 0; q < 4; ++q) acc[ct][q] += bb;
        }
        float mean[4], rstd[4];
#pragma unroll
        for (int q = 0; q < 4; ++q) {
            float s = 0.f, s2 = 0.f;
#pragma unroll
            for (int ct = 0; ct < 16; ++ct) { float v = acc[ct][q]; s += v; s2 += v * v; }
#pragma unroll
            for (int m = 1; m < 16; m <<= 1) { s += __shfl_xor(s, m, 64); s2 += __shfl_xor(s2, m, 64); }
            float mu = s * (1.0f / H);
            mean[q] = mu;
            rstd[q] = rsqrtf(s2 * (1.0f / H) - mu * mu + LN_EPS);
        }
#pragma unroll
        for (int ct = 0; ct < 16; ++ct) {
            int col = ct * 16 + lr;
            float gg = g2[col], bb = be2[col];
#pragma unroll
            for (int q = 0; q < 4; ++q) {
                float nv = (acc[ct][q] - mean[q]) * rstd[q] * gg + bb;
                dtile[wv * 16 + lg * 4 + q][col] = f2bf(nv);
            }
        }
    }
    __syncthreads();

    // ---- phase B: GRU; 48-col tile, register-prefetch (issue-early, commit-late) ----
    {
        bf16x8 ah[8];
        const unsigned short* lp = &dtile[wv * 16 + lr][0] + lg * 8;
#pragma unroll
        for (int ks = 0; ks < 8; ++ks) ah[ks] = __builtin_bit_cast(bf16x8, *(const u16x8*)(lp + ks * 32));
        u16x8 pre[6];
        auto issue = [&](int ct) {
#pragma unroll
            for (int j = 0; j < 6; ++j) {
                int i = t + j * 256;          // 0..1535
                int col = i >> 5;             // 0..47 (gate*16 + c)
                int off = (i & 31) * 8;       // shorts
                int gate = col >> 4, c = col & 15;
                pre[j] = *(const u16x8*)(Wg + ((gate * 256 + ct * 16 + c) * 256 + off));
            }
        };
        auto commit = [&]() {
#pragma unroll
            for (int j = 0; j < 6; ++j) {
                int i = t + j * 256;
                int col = i >> 5;
                int off = (i & 31) * 8;
                *(u16x8*)(&wbuf[col * GRU_STR + off]) = pre[j];
            }
        };
        issue(0);
        commit();
        __syncthreads();
        for (int ct = 0; ct < 16; ++ct) {
            if (ct < 15) issue(ct + 1);   // loads in flight during MFMAs below
            f32x4 aR = (f32x4){0.f, 0.f, 0.f, 0.f};
            f32x4 aZ = aR, aN = aR;
            const unsigned short* base = wbuf + lr * GRU_STR + lg * 8;
#pragma unroll
            for (int ks = 0; ks < 8; ++ks) {
                bf16x8 b0 = __builtin_bit_cast(bf16x8, *(const u16x8*)(base + ks * 32));
                bf16x8 b1 = __builtin_bit_cast(bf16x8, *(const u16x8*)(base + 16 * GRU_STR + ks * 32));
                bf16x8 b2v = __builtin_bit_cast(bf16x8, *(const u16x8*)(base + 32 * GRU_STR + ks * 32));
                aR = __builtin_amdgcn_mfma_f32_16x16x32_bf16(ah[ks], b0, aR, 0, 0, 0);
                aZ = __builtin_amdgcn_mfma_f32_16x16x32_bf16(ah[ks], b1, aZ, 0, 0, 0);
                aN = __builtin_amdgcn_mfma_f32_16x16x32_bf16(ah[ks], b2v, aN, 0, 0, 0);
            }
            int col = ct * 16 + lr;
            float bR = bih[col] + bhh[col];
            float bZ = bih[col + 256] + bhh[col + 256];
            float bN = bih[col + 512];
            float hN = bhh[col + 512];
#pragma unroll
            for (int q = 0; q < 4; ++q) {
                float r = fsig(aR[q] + bR);
                float z = fsig(aZ[q] + bZ);
                float nn = ftanh(aN[q] + bN + r * hN);
                dtile[wv * 16 + lg * 4 + q][col] = f2bf((1.0f - z) * nn);
            }
            __syncthreads();              // all waves done reading wbuf[ct]
            if (ct < 15) {
                commit();                 // prefetched regs -> wbuf
                __syncthreads();          // wbuf[ct+1] ready
            }
        }
    }

    // ---- phase C: d1 = relu([temporal, x] @ Wd1 + bd1) -> dtile ----
    {
        bf16x8 ad[9];
        const unsigned short* lp = &dtile[wv * 16 + lr][0] + lg * 8;
#pragma unroll
        for (int ks = 0; ks < 8; ++ks) ad[ks] = __builtin_bit_cast(bf16x8, *(const u16x8*)(lp + ks * 32));
        ad[8] = __builtin_bit_cast(bf16x8, *(const u16x8*)(xb + (long long)arow * 32 + lg * 8));
        __syncthreads();
        f32x4 acc[16];
#pragma unroll
        for (int ct = 0; ct < 16; ++ct) acc[ct] = (f32x4){0.f, 0.f, 0.f, 0.f};
        for (int ct = 0; ct < 16; ++ct) {
            const unsigned short* wr = W1T + (ct * 16 + lr) * 288 + lg * 8;
#pragma unroll
            for (int ks = 0; ks < 9; ++ks) {
                bf16x8 bfv = __builtin_bit_cast(bf16x8, *(const u16x8*)(wr + ks * 32));
                acc[ct] = __builtin_amdgcn_mfma_f32_16x16x32_bf16(ad[ks], bfv, acc[ct], 0, 0, 0);
            }
        }
#pragma unroll
        for (int ct = 0; ct < 16; ++ct) {
            float bb = bd1[ct * 16 + lr];
#pragma unroll
            for (int q = 0; q < 4; ++q) {
                float v = fmaxf(acc[ct][q] + bb, 0.0f);
                dtile[wv * 16 + lg * 4 + q][ct * 16 + lr] = f2bf(v);
            }
        }
    }
    __syncthreads();

    // ---- phase D: d2 = relu(d1 @ Wd2 + bd2); pred = clip(d2 @ Wd3 + bd3) ----
    bf16x8 af[8];
    const unsigned short* lp = &dtile[wv * 16 + lr][0] + lg * 8;
#pragma unroll
    for (int ks = 0; ks < 8; ++ks) af[ks] = __builtin_bit_cast(bf16x8, *(const u16x8*)(lp + ks * 32));
    f32x4 acc[8];
#pragma unroll
    for (int ct = 0; ct < 8; ++ct) acc[ct] = (f32x4){0.f, 0.f, 0.f, 0.f};
    for (int ct = 0; ct < 8; ++ct) {
        const unsigned short* wr = Wd2T + (ct * 16 + lr) * H + lg * 8;
#pragma unroll
        for (int ks = 0; ks < 8; ++ks) {
            bf16x8 bfv = __builtin_bit_cast(bf16x8, *(const u16x8*)(wr + ks * 32));
            acc[ct] = __builtin_amdgcn_mfma_f32_16x16x32_bf16(af[ks], bfv, acc[ct], 0, 0, 0);
        }
    }
    float p0[4] = {0.f, 0.f, 0.f, 0.f}, p1[4] = {0.f, 0.f, 0.f, 0.f};
#pragma unroll
    for (int ct = 0; ct < 8; ++ct) {
        int col = ct * 16 + lr;
        float bb = bd2[col];
        float2 w3 = *(const float2*)(Wd3 + col * 2);
#pragma unroll
        for (int q = 0; q < 4; ++q) {
            float v = fmaxf(acc[ct][q] + bb, 0.0f);
            p0[q] = fmaf(v, w3.x, p0[q]);
            p1[q] = fmaf(v, w3.y, p1[q]);
        }
    }
#pragma unroll
    for (int q = 0; q < 4; ++q) {
#pragma unroll
        for (int m = 1; m < 16; m <<= 1) {
            p0[q] += __shfl_xor(p0[q], m, 64);
            p1[q] += __shfl_xor(p1[q], m, 64);
        }
    }
    if (lr == 0) {
#pragma unroll
        for (int q = 0; q < 4; ++q) {
            int row = rb + lg * 4 + q;
            if (row < N_NODES) {
                float a = fminf(fmaxf(p0[q] + bd3[0], -5.0f), 5.0f);
                float b = fminf(fmaxf(p1[q] + bd3[1], -5.0f), 5.0f);
                out[(long long)row * 2] = a;
                out[(long long)row * 2 + 1] = b;
            }
        }
    }
}

extern "C" void kernel_launch(void* const* d_in, const int* in_sizes, int n_in,
                              void* d_out, int out_size, void* d_ws, size_t ws_size,
                              hipStream_t stream) {
    const float* x   = (const float*)d_in[0];
    const void*  ei  = d_in[1];
    const float* ew  = (const float*)d_in[2];
    const float* W1  = (const float*)d_in[3];
    const float* b1  = (const float*)d_in[4];
    const float* g1  = (const float*)d_in[5];
    const float* be1 = (const float*)d_in[6];
    const float* W2  = (const float*)d_in[7];
    const float* b2  = (const float*)d_in[8];
    const float* g2  = (const float*)d_in[9];
    const float* be2 = (const float*)d_in[10];
    const float* Wih = (const float*)d_in[11];
    const float* bih = (const float*)d_in[13];
    const float* bhh = (const float*)d_in[14];
    const float* Wd1 = (const float*)d_in[15];
    const float* bd1 = (const float*)d_in[16];
    const float* Wd2 = (const float*)d_in[17];
    const float* bd2 = (const float*)d_in[18];
    const float* Wd3 = (const float*)d_in[19];
    const float* bd3 = (const float*)d_in[20];
    float* out = (float*)d_out;

    char* w = (char*)d_ws;
    size_t pos = 0;
    auto carve = [&](size_t bytes) -> void* {
        void* p = w + pos;
        pos += (bytes + 255) & ~(size_t)255;
        return p;
    };
    int*   bcursor = (int*)carve(sizeof(int) * 512);
    float* dis     = (float*)carve(sizeof(float) * N_NODES);
    int*   offs    = (int*)carve(sizeof(int) * N_NODES);
    int*   oend    = (int*)carve(sizeof(int) * N_NODES);
    unsigned long long* stage = (unsigned long long*)carve(8 * (size_t)NB * CAP);
    unsigned* csr = (unsigned*)carve(4 * (size_t)NB * CAP);
    unsigned short* xpb  = (unsigned short*)carve(2 * (size_t)N_NODES * DIN);
    unsigned short* xb   = (unsigned short*)carve(2 * (size_t)N_NODES * 32);
    unsigned short* Wg   = (unsigned short*)carve(2 * 768 * 256);
    unsigned short* W2T  = (unsigned short*)carve(2 * 256 * 256);
    unsigned short* Wd1T = (unsigned short*)carve(2 * 256 * 288);
    unsigned short* Wd2T = (unsigned short*)carve(2 * 128 * 256);
    unsigned short* Abf = (unsigned short*)carve(2 * (size_t)N_NODES * H);  // h1p bf16
    unsigned short* Bbf = (unsigned short*)carve(2 * (size_t)N_NODES * H);  // agg2 bf16
    (void)pos; (void)ws_size; (void)in_sizes; (void)n_in; (void)out_size;

    int nbm = (N_NODES + 63) / 64;        // 782
    int nwp = (768 * 256 + 256 * 256 + 256 * 288 + 128 * 256 + N_NODES * 32 + 512 + 255) / 256;

    k_wprep<<<nwp, 256, 0, stream>>>(Wih, W2, Wd1, Wd2, x, Wg, W2T, Wd1T, Wd2T, xb, bcursor);
    k_msplit<<<NTILES, 256, 0, stream>>>(ei, ew, bcursor, stage);
    k_bfin<<<NB, 256, 0, stream>>>(stage, bcursor, x, dis, offs, oend, csr, xpb);
    k_l1<<<N_NODES / RPB, 256, 0, stream>>>(xpb, offs, oend, csr, dis, W1, b1, g1, be1, Abf);
    k_spmm<<<N_NODES / 4, 256, 0, stream>>>(Abf, Bbf, offs, oend, csr, dis);
    k_lgd<<<nbm, 256, 0, stream>>>(Bbf, W2T, b2, g2, be2, Wg, bih, bhh,
                                   Wd1T, bd1, Wd2T, bd2, Wd3, bd3, xb, out);
}

// Round 18
// 353.011 us; speedup vs baseline: 1.0866x; 1.0016x over previous
//
#include <hip/hip_runtime.h>
#include <math.h>

#define N_NODES 50000
#define N_EDGES 1600000
#define DIN 16
#define H 256
#define RPB 16
#define LN_EPS 1e-5f
#define FIXS 8388608.0f   // 2^23
#define NB 391            // buckets of 128 dst nodes
#define CAP 5120          // bucket capacity
#define TILEA 4096
#define NTILES 391
#define GRU_COLS 48       // 3 gates x 16 cols per ct step
#define GRU_STR 272       // wbuf col stride in shorts
#define DSTR 264          // dtile row stride in shorts

typedef __attribute__((ext_vector_type(8))) unsigned short u16x8;
typedef __attribute__((ext_vector_type(8))) __bf16 bf16x8;
typedef __attribute__((ext_vector_type(4))) float f32x4;

__device__ inline unsigned short f2bf(float f) {
    unsigned u = __builtin_bit_cast(unsigned, f);
    return (unsigned short)((u + 0x7FFFu + ((u >> 16) & 1u)) >> 16);
}
__device__ inline float bf2f(unsigned short u) {
    return __builtin_bit_cast(float, ((unsigned)u) << 16);
}
__device__ inline float fsig(float x) { return 1.0f / (1.0f + __expf(-x)); }
__device__ inline float ftanh(float x) { return 2.0f / (1.0f + __expf(-2.0f * x)) - 1.0f; }

// ---------------- merged weight prep + xb + bcursor zero ----------------
__global__ void k_wprep(const float* Wih, const float* W2, const float* Wd1, const float* Wd2,
                        const float* x, unsigned short* Wg, unsigned short* W2T,
                        unsigned short* Wd1T, unsigned short* Wd2T, unsigned short* xb,
                        int* bcursor) {
    int idx = blockIdx.x * blockDim.x + threadIdx.x;
    if (idx < 768 * 256) { Wg[idx] = f2bf(Wih[idx]); return; }
    idx -= 768 * 256;
    if (idx < 256 * 256) { int k = idx >> 8, n = idx & 255; W2T[n * 256 + k] = f2bf(W2[idx]); return; }
    idx -= 256 * 256;
    if (idx < 256 * 288) {
        int n = idx / 288, k = idx % 288;
        Wd1T[idx] = (k < 272) ? f2bf(Wd1[k * 256 + n]) : (unsigned short)0;
        return;
    }
    idx -= 256 * 288;
    if (idx < 128 * 256) { int k = idx >> 7, n = idx & 127; Wd2T[n * 256 + k] = f2bf(Wd2[idx]); return; }
    idx -= 128 * 256;
    if (idx < N_NODES * 32) {
        int row = idx >> 5, j = idx & 31;
        xb[idx] = (j < 16) ? f2bf(x[row * DIN + j]) : (unsigned short)0;
        return;
    }
    idx -= N_NODES * 32;
    if (idx < 512) bcursor[idx] = 0;
}

// ---------------- single-pass multisplit into fixed-capacity bucket regions ----------------
// packed u64 = ew(32) << 32 | dstlow7 << 16 | src(16); edge dtype detected inline
__global__ __launch_bounds__(256) void k_msplit(const void* ei, const float* ew,
                                                int* bcursor, unsigned long long* stage) {
    __shared__ int bh[512], bscn[512], cur[512], gbase[512];
    __shared__ int ws4[4];
    __shared__ unsigned long long sdata[TILEA];
    __shared__ unsigned short sbkt[TILEA];
    int t = threadIdx.x;
    long long base = (long long)blockIdx.x * TILEA;
    int nhere = (int)(((long long)N_EDGES - base) < TILEA ? (N_EDGES - base) : TILEA);
    for (int i = t; i < 512; i += 256) bh[i] = 0;
    bool f64;
    {
        const long long* p = (const long long*)ei;
        f64 = true;
        for (int i = 0; i < 8; ++i) { long long v = p[i]; if (v < 0 || v >= N_NODES) f64 = false; }
    }
    __syncthreads();
    unsigned long long vreg[TILEA / 256];
    int breg[TILEA / 256];
#pragma unroll
    for (int k = 0; k < TILEA / 256; ++k) {
        long long e = base + k * 256 + t;
        if (e < N_EDGES) {
            int s, d;
            if (f64) {
                const long long* p = (const long long*)ei;
                s = (int)p[e]; d = (int)p[N_EDGES + e];
            } else {
                const int* p = (const int*)ei;
                s = p[e]; d = p[N_EDGES + e];
            }
            unsigned wbits = __builtin_bit_cast(unsigned, ew[e]);
            vreg[k] = ((unsigned long long)wbits << 32) |
                      ((unsigned long long)(d & 127) << 16) | (unsigned)(s & 0xFFFF);
            breg[k] = d >> 7;
            atomicAdd(&bh[breg[k]], 1);
        } else breg[k] = -1;
    }
    __syncthreads();
    int a0 = bh[2 * t], a1 = bh[2 * t + 1];
    int s = a0 + a1;
    int lane = t & 63, wv = t >> 6;
    int sc = s;
    for (int d = 1; d < 64; d <<= 1) { int u = __shfl_up(sc, d, 64); if (lane >= d) sc += u; }
    if (lane == 63) ws4[wv] = sc;
    __syncthreads();
    int wpre = 0;
    for (int i = 0; i < wv; ++i) wpre += ws4[i];
    int excl = wpre + sc - s;
    bscn[2 * t] = excl;      cur[2 * t] = excl;
    bscn[2 * t + 1] = excl + a0; cur[2 * t + 1] = excl + a0;
    __syncthreads();
    for (int i = t; i < NB; i += 256) {
        int c = bh[i];
        if (c) gbase[i] = atomicAdd(&bcursor[i], c);
    }
    __syncthreads();
#pragma unroll
    for (int k = 0; k < TILEA / 256; ++k) {
        if (breg[k] >= 0) {
            int p = atomicAdd(&cur[breg[k]], 1);
            sdata[p] = vreg[k];
            sbkt[p] = (unsigned short)breg[k];
        }
    }
    __syncthreads();
    for (int i = t; i < nhere; i += 256) {
        int b = sbkt[i];
        stage[(long long)b * CAP + gbase[b] + (i - bscn[b])] = sdata[i];
    }
}

// ---------------- fused: degree/dis + scan -> offs/oend + CSR placement + xpb ----------------
__global__ __launch_bounds__(256) void k_bfin(const unsigned long long* __restrict__ stage,
                                              const int* __restrict__ bcursor,
                                              const float* __restrict__ x,
                                              float* __restrict__ dis,
                                              int* __restrict__ offs, int* __restrict__ oend,
                                              unsigned* __restrict__ csr,
                                              unsigned short* __restrict__ xpb) {
    __shared__ unsigned long long acc[128];
    __shared__ int sc[128];
    __shared__ int cur[128];
    __shared__ float sdis[128];
    int b = blockIdx.x, t = threadIdx.x;
    if (t < 128) acc[t] = 0ULL;
    __syncthreads();
    long long e0 = (long long)b * CAP;
    int n = bcursor[b];
    for (int i = t; i < n; i += 256) {
        unsigned long long v = stage[e0 + i];
        int nl = (int)((v >> 16) & 127);
        float w = __builtin_bit_cast(float, (unsigned)(v >> 32));
        atomicAdd(&acc[nl], (1ULL << 43) | (unsigned long long)llrintf(w * FIXS));
    }
    __syncthreads();
    int mycnt = 0;
    if (t < 128) {
        unsigned long long v = acc[t];
        mycnt = (int)(v >> 43);
        sc[t] = mycnt;
        float dv = rsqrtf((float)(v & ((1ULL << 43) - 1)) * (1.0f / FIXS) + 2.0f);
        sdis[t] = dv;
        int node = (b << 7) + t;
        if (node < N_NODES) dis[node] = dv;
    }
    __syncthreads();
    for (int d = 1; d < 128; d <<= 1) {
        int v = 0;
        if (t < 128 && t >= d) v = sc[t - d];
        __syncthreads();
        if (t < 128 && t >= d) sc[t] += v;
        __syncthreads();
    }
    if (t < 128) {
        int excl = sc[t] - mycnt;
        cur[t] = excl;
        int node = (b << 7) + t;
        if (node < N_NODES) {
            offs[node] = (int)(e0 + excl);
            oend[node] = (int)(e0 + excl + mycnt);
        }
    }
    __syncthreads();
    for (int i = t; i < n; i += 256) {
        unsigned long long v = stage[e0 + i];
        int nl = (int)((v >> 16) & 127);
        int p = atomicAdd(&cur[nl], 1);
        float w = __builtin_bit_cast(float, (unsigned)(v >> 32));
        csr[e0 + p] = ((unsigned)f2bf(w) << 16) | (unsigned)(v & 0xFFFFu);
    }
    // xp = bf16(dis * x) for this bucket's nodes
    for (int i = t; i < 128 * DIN; i += 256) {
        int nl = i >> 4, dd = i & 15;
        int node = (b << 7) + nl;
        if (node < N_NODES) xpb[node * DIN + dd] = f2bf(sdis[nl] * x[node * DIN + dd]);
    }
}

// ---------------- fused layer-1: aggregation (DIN) + GEMM(16->256) + bias + LN + relu + dis-scale ----------------
__global__ __launch_bounds__(256) void k_l1(const unsigned short* __restrict__ xpb,
        const int* __restrict__ offs, const int* __restrict__ oend,
        const unsigned* __restrict__ csr, const float* __restrict__ dis,
        const float* __restrict__ W, const float* __restrict__ bias,
        const float* __restrict__ g, const float* __restrict__ be,
        unsigned short* __restrict__ out) {
    __shared__ float s[RPB][H + 1];
    __shared__ float smu[RPB], srs[RPB];
    int t = threadIdx.x;
    long long rowbase = (long long)blockIdx.x * RPB;
    {
        int r = blockIdx.x * 16 + (t >> 4);
        int dd = t & 15;
        float di = dis[r];
        float xself = bf2f(xpb[(long long)r * DIN + dd]);
        float acc = 0.0f;
        int e0 = offs[r], e1 = oend[r];
        for (int e = e0; e < e1; e += 8) {
            unsigned vv[8];
#pragma unroll
            for (int j = 0; j < 8; ++j) {
                int idx = e + j;
                vv[j] = (idx < e1) ? csr[idx] : (unsigned)r;
            }
            float xx[8];
#pragma unroll
            for (int j = 0; j < 8; ++j) {
                int sidx = (int)(vv[j] & 0xFFFFu);
                xx[j] = bf2f(xpb[(long long)sidx * DIN + dd]);
            }
#pragma unroll
            for (int j = 0; j < 8; ++j) {
                float c = bf2f((unsigned short)(vv[j] >> 16));
                acc = fmaf(c, xx[j], acc);
            }
        }
        s[t >> 4][dd] = di * acc + 2.0f * di * xself;
    }
    __syncthreads();
    float acc2[RPB];
    float bb0 = bias[t];
#pragma unroll
    for (int r = 0; r < RPB; ++r) acc2[r] = bb0;
    for (int k = 0; k < DIN; ++k) {
        float wv = W[k * H + t];
#pragma unroll
        for (int r = 0; r < RPB; ++r) acc2[r] = fmaf(s[r][k], wv, acc2[r]);
    }
    __syncthreads();
#pragma unroll
    for (int r = 0; r < RPB; ++r) s[r][t] = acc2[r];
    __syncthreads();
    int lane = t & 63, wv2 = t >> 6;
    for (int rr = wv2; rr < RPB; rr += 4) {
        float v0 = s[rr][lane], v1 = s[rr][lane + 64], v2 = s[rr][lane + 128], v3 = s[rr][lane + 192];
        float sm = v0 + v1 + v2 + v3;
        float sq = v0 * v0 + v1 * v1 + v2 * v2 + v3 * v3;
        for (int d = 32; d; d >>= 1) {
            sm += __shfl_down(sm, d, 64);
            sq += __shfl_down(sq, d, 64);
        }
        if (lane == 0) {
            float mu = sm * (1.0f / H);
            float var = sq * (1.0f / H) - mu * mu;
            smu[rr] = mu;
            srs[rr] = rsqrtf(var + LN_EPS);
        }
    }
    __syncthreads();
    float gg = g[t], bb = be[t];
#pragma unroll
    for (int r = 0; r < RPB; ++r) {
        float h = fmaxf((acc2[r] - smu[r]) * srs[r] * gg + bb, 0.0f);
        out[(rowbase + r) * H + t] = f2bf(h * dis[rowbase + r]);
    }
}

// ---------------- SpMM in H space: full-row gather, 16-deep MLP ----------------
__global__ __launch_bounds__(256) void k_spmm(const unsigned short* __restrict__ hin,
                                              unsigned short* __restrict__ hout,
                                              const int* __restrict__ offs,
                                              const int* __restrict__ oend,
                                              const unsigned* __restrict__ csr,
                                              const float* __restrict__ dis) {
    int t = threadIdx.x;
    int wv = t >> 6, lane = t & 63;
    int row = blockIdx.x * 4 + wv;
    const ushort4* h4 = (const ushort4*)hin;
    float di = dis[row];
    ushort4 vs = h4[(long long)row * 64 + lane];
    float a0 = 0.f, a1 = 0.f, a2 = 0.f, a3 = 0.f;
    int e0 = offs[row], e1 = oend[row];
    for (int e = e0; e < e1; e += 16) {
        unsigned vv[16];
#pragma unroll
        for (int j = 0; j < 16; ++j) {
            int idx = e + j;
            vv[j] = (idx < e1) ? csr[idx] : (unsigned)row;
        }
        ushort4 uu[16];
#pragma unroll
        for (int j = 0; j < 16; ++j) {
            int s = (int)(vv[j] & 0xFFFFu);
            uu[j] = h4[(long long)s * 64 + lane];
        }
#pragma unroll
        for (int j = 0; j < 16; ++j) {
            float c = bf2f((unsigned short)(vv[j] >> 16));
            a0 = fmaf(c, bf2f(uu[j].x), a0);
            a1 = fmaf(c, bf2f(uu[j].y), a1);
            a2 = fmaf(c, bf2f(uu[j].z), a2);
            a3 = fmaf(c, bf2f(uu[j].w), a3);
        }
    }
    ushort4 o;
    o.x = f2bf(di * a0 + 2.0f * di * bf2f(vs.x));
    o.y = f2bf(di * a1 + 2.0f * di * bf2f(vs.y));
    o.z = f2bf(di * a2 + 2.0f * di * bf2f(vs.z));
    o.w = f2bf(di * a3 + 2.0f * di * bf2f(vs.w));
    ((ushort4*)hout)[(long long)row * 64 + lane] = o;
}

// ---------------- fused tail: LN(mfma) -> GRU(48-col LDS tile, reg-prefetch) -> decoder ----------------
// frag layout (16x16x32 bf16): A lane l: row l&15, k=8*(l>>4)+j ; B lane l: col l&15, same k ;
// D lane l: col l&15, row 4*(l>>4)+reg
// Phases A/C/D interleave 2 independent accumulator chains per wave (MFMA dep-latency hiding).
__global__ __launch_bounds__(256) void k_lgd(
        const unsigned short* __restrict__ Bbf,
        const unsigned short* __restrict__ W2T, const float* __restrict__ b2,
        const float* __restrict__ g2, const float* __restrict__ be2,
        const unsigned short* __restrict__ Wg, const float* __restrict__ bih,
        const float* __restrict__ bhh,
        const unsigned short* __restrict__ W1T, const float* __restrict__ bd1,
        const unsigned short* __restrict__ Wd2T, const float* __restrict__ bd2,
        const float* __restrict__ Wd3, const float* __restrict__ bd3,
        const unsigned short* __restrict__ xb, float* __restrict__ out) {
    __shared__ unsigned short wbuf[GRU_COLS * GRU_STR];   // 26.1 KB
    __shared__ unsigned short dtile[64][DSTR];            // 33.8 KB (total 59.9 -> 2 blocks/CU)
    int t = threadIdx.x;
    int wv = t >> 6, l = t & 63;
    int lr = l & 15, lg = l >> 4;
    int rb = blockIdx.x * 64 + wv * 16;
    int arow = rb + lr; if (arow >= N_NODES) arow = N_NODES - 1;

    // ---- phase A: h2 = LN(Bbf @ W2 + b2) -> dtile ----
    {
        bf16x8 af[8];
        const unsigned short* ap = Bbf + (long long)arow * H + lg * 8;
#pragma unroll
        for (int ks = 0; ks < 8; ++ks) af[ks] = __builtin_bit_cast(bf16x8, *(const u16x8*)(ap + ks * 32));
        f32x4 acc[16];
#pragma unroll
        for (int ct = 0; ct < 16; ++ct) acc[ct] = (f32x4){0.f, 0.f, 0.f, 0.f};
#pragma unroll
        for (int ct = 0; ct < 16; ct += 2) {
            const unsigned short* wr0 = W2T + ((ct + 0) * 16 + lr) * H + lg * 8;
            const unsigned short* wr1 = W2T + ((ct + 1) * 16 + lr) * H + lg * 8;
#pragma unroll
            for (int ks = 0; ks < 8; ++ks) {
                bf16x8 b0 = __builtin_bit_cast(bf16x8, *(const u16x8*)(wr0 + ks * 32));
                bf16x8 b1 = __builtin_bit_cast(bf16x8, *(const u16x8*)(wr1 + ks * 32));
                acc[ct + 0] = __builtin_amdgcn_mfma_f32_16x16x32_bf16(af[ks], b0, acc[ct + 0], 0, 0, 0);
                acc[ct + 1] = __builtin_amdgcn_mfma_f32_16x16x32_bf16(af[ks], b1, acc[ct + 1], 0, 0, 0);
            }
        }
#pragma unroll
        for (int ct = 0; ct < 16; ++ct) {
            float bb = b2[ct * 16 + lr];
#pragma unroll
            for (int q = 0; q < 4; ++q) acc[ct][q] += bb;
        }
        float mean[4], rstd[4];
#pragma unroll
        for (int q = 0; q < 4; ++q) {
            float s = 0.f, s2 = 0.f;
#pragma unroll
            for (int ct = 0; ct < 16; ++ct) { float v = acc[ct][q]; s += v; s2 += v * v; }
#pragma unroll
            for (int m = 1; m < 16; m <<= 1) { s += __shfl_xor(s, m, 64); s2 += __shfl_xor(s2, m, 64); }
            float mu = s * (1.0f / H);
            mean[q] = mu;
            rstd[q] = rsqrtf(s2 * (1.0f / H) - mu * mu + LN_EPS);
        }
#pragma unroll
        for (int ct = 0; ct < 16; ++ct) {
            int col = ct * 16 + lr;
            float gg = g2[col], bb = be2[col];
#pragma unroll
            for (int q = 0; q < 4; ++q) {
                float nv = (acc[ct][q] - mean[q]) * rstd[q] * gg + bb;
                dtile[wv * 16 + lg * 4 + q][col] = f2bf(nv);
            }
        }
    }
    __syncthreads();

    // ---- phase B: GRU; 48-col tile, register-prefetch (issue-early, commit-late) ----
    {
        bf16x8 ah[8];
        const unsigned short* lp = &dtile[wv * 16 + lr][0] + lg * 8;
#pragma unroll
        for (int ks = 0; ks < 8; ++ks) ah[ks] = __builtin_bit_cast(bf16x8, *(const u16x8*)(lp + ks * 32));
        u16x8 pre[6];
        auto issue = [&](int ct) {
#pragma unroll
            for (int j = 0; j < 6; ++j) {
                int i = t + j * 256;          // 0..1535
                int col = i >> 5;             // 0..47 (gate*16 + c)
                int off = (i & 31) * 8;       // shorts
                int gate = col >> 4, c = col & 15;
                pre[j] = *(const u16x8*)(Wg + ((gate * 256 + ct * 16 + c) * 256 + off));
            }
        };
        auto commit = [&]() {
#pragma unroll
            for (int j = 0; j < 6; ++j) {
                int i = t + j * 256;
                int col = i >> 5;
                int off = (i & 31) * 8;
                *(u16x8*)(&wbuf[col * GRU_STR + off]) = pre[j];
            }
        };
        issue(0);
        commit();
        __syncthreads();
        for (int ct = 0; ct < 16; ++ct) {
            if (ct < 15) issue(ct + 1);   // loads in flight during MFMAs below
            f32x4 aR = (f32x4){0.f, 0.f, 0.f, 0.f};
            f32x4 aZ = aR, aN = aR;
            const unsigned short* base = wbuf + lr * GRU_STR + lg * 8;
#pragma unroll
            for (int ks = 0; ks < 8; ++ks) {
                bf16x8 b0 = __builtin_bit_cast(bf16x8, *(const u16x8*)(base + ks * 32));
                bf16x8 b1 = __builtin_bit_cast(bf16x8, *(const u16x8*)(base + 16 * GRU_STR + ks * 32));
                bf16x8 b2v = __builtin_bit_cast(bf16x8, *(const u16x8*)(base + 32 * GRU_STR + ks * 32));
                aR = __builtin_amdgcn_mfma_f32_16x16x32_bf16(ah[ks], b0, aR, 0, 0, 0);
                aZ = __builtin_amdgcn_mfma_f32_16x16x32_bf16(ah[ks], b1, aZ, 0, 0, 0);
                aN = __builtin_amdgcn_mfma_f32_16x16x32_bf16(ah[ks], b2v, aN, 0, 0, 0);
            }
            int col = ct * 16 + lr;
            float bR = bih[col] + bhh[col];
            float bZ = bih[col + 256] + bhh[col + 256];
            float bN = bih[col + 512];
            float hN = bhh[col + 512];
#pragma unroll
            for (int q = 0; q < 4; ++q) {
                float r = fsig(aR[q] + bR);
                float z = fsig(aZ[q] + bZ);
                float nn = ftanh(aN[q] + bN + r * hN);
                dtile[wv * 16 + lg * 4 + q][col] = f2bf((1.0f - z) * nn);
            }
            __syncthreads();              // all waves done reading wbuf[ct]
            if (ct < 15) {
                commit();                 // prefetched regs -> wbuf
                __syncthreads();          // wbuf[ct+1] ready
            }
        }
    }

    // ---- phase C: d1 = relu([temporal, x] @ Wd1 + bd1) -> dtile ----
    {
        bf16x8 ad[9];
        const unsigned short* lp = &dtile[wv * 16 + lr][0] + lg * 8;
#pragma unroll
        for (int ks = 0; ks < 8; ++ks) ad[ks] = __builtin_bit_cast(bf16x8, *(const u16x8*)(lp + ks * 32));
        ad[8] = __builtin_bit_cast(bf16x8, *(const u16x8*)(xb + (long long)arow * 32 + lg * 8));
        __syncthreads();
        f32x4 acc[16];
#pragma unroll
        for (int ct = 0; ct < 16; ++ct) acc[ct] = (f32x4){0.f, 0.f, 0.f, 0.f};
#pragma unroll
        for (int ct = 0; ct < 16; ct += 2) {
            const unsigned short* wr0 = W1T + ((ct + 0) * 16 + lr) * 288 + lg * 8;
            const unsigned short* wr1 = W1T + ((ct + 1) * 16 + lr) * 288 + lg * 8;
#pragma unroll
            for (int ks = 0; ks < 9; ++ks) {
                bf16x8 b0 = __builtin_bit_cast(bf16x8, *(const u16x8*)(wr0 + ks * 32));
                bf16x8 b1 = __builtin_bit_cast(bf16x8, *(const u16x8*)(wr1 + ks * 32));
                acc[ct + 0] = __builtin_amdgcn_mfma_f32_16x16x32_bf16(ad[ks], b0, acc[ct + 0], 0, 0, 0);
                acc[ct + 1] = __builtin_amdgcn_mfma_f32_16x16x32_bf16(ad[ks], b1, acc[ct + 1], 0, 0, 0);
            }
        }
#pragma unroll
        for (int ct = 0; ct < 16; ++ct) {
            float bb = bd1[ct * 16 + lr];
#pragma unroll
            for (int q = 0; q < 4; ++q) {
                float v = fmaxf(acc[ct][q] + bb, 0.0f);
                dtile[wv * 16 + lg * 4 + q][ct * 16 + lr] = f2bf(v);
            }
        }
    }
    __syncthreads();

    // ---- phase D: d2 = relu(d1 @ Wd2 + bd2); pred = clip(d2 @ Wd3 + bd3) ----
    bf16x8 af[8];
    const unsigned short* lp = &dtile[wv * 16 + lr][0] + lg * 8;
#pragma unroll
    for (int ks = 0; ks < 8; ++ks) af[ks] = __builtin_bit_cast(bf16x8, *(const u16x8*)(lp + ks * 32));
    f32x4 acc[8];
#pragma unroll
    for (int ct = 0; ct < 8; ++ct) acc[ct] = (f32x4){0.f, 0.f, 0.f, 0.f};
#pragma unroll
    for (int ct = 0; ct < 8; ct += 2) {
        const unsigned short* wr0 = Wd2T + ((ct + 0) * 16 + lr) * H + lg * 8;
        const unsigned short* wr1 = Wd2T + ((ct + 1) * 16 + lr) * H + lg * 8;
#pragma unroll
        for (int ks = 0; ks < 8; ++ks) {
            bf16x8 b0 = __builtin_bit_cast(bf16x8, *(const u16x8*)(wr0 + ks * 32));
            bf16x8 b1 = __builtin_bit_cast(bf16x8, *(const u16x8*)(wr1 + ks * 32));
            acc[ct + 0] = __builtin_amdgcn_mfma_f32_16x16x32_bf16(af[ks], b0, acc[ct + 0], 0, 0, 0);
            acc[ct + 1] = __builtin_amdgcn_mfma_f32_16x16x32_bf16(af[ks], b1, acc[ct + 1], 0, 0, 0);
        }
    }
    float p0[4] = {0.f, 0.f, 0.f, 0.f}, p1[4] = {0.f, 0.f, 0.f, 0.f};
#pragma unroll
    for (int ct = 0; ct < 8; ++ct) {
        int col = ct * 16 + lr;
        float bb = bd2[col];
        float2 w3 = *(const float2*)(Wd3 + col * 2);
#pragma unroll
        for (int q = 0; q < 4; ++q) {
            float v = fmaxf(acc[ct][q] + bb, 0.0f);
            p0[q] = fmaf(v, w3.x, p0[q]);
            p1[q] = fmaf(v, w3.y, p1[q]);
        }
    }
#pragma unroll
    for (int q = 0; q < 4; ++q) {
#pragma unroll
        for (int m = 1; m < 16; m <<= 1) {
            p0[q] += __shfl_xor(p0[q], m, 64);
            p1[q] += __shfl_xor(p1[q], m, 64);
        }
    }
    if (lr == 0) {
#pragma unroll
        for (int q = 0; q < 4; ++q) {
            int row = rb + lg * 4 + q;
            if (row < N_NODES) {
                float a = fminf(fmaxf(p0[q] + bd3[0], -5.0f), 5.0f);
                float b = fminf(fmaxf(p1[q] + bd3[1], -5.0f), 5.0f);
                out[(long long)row * 2] = a;
                out[(long long)row * 2 + 1] = b;
            }
        }
    }
}

extern "C" void kernel_launch(void* const* d_in, const int* in_sizes, int n_in,
                              void* d_out, int out_size, void* d_ws, size_t ws_size,
                              hipStream_t stream) {
    const float* x   = (const float*)d_in[0];
    const void*  ei  = d_in[1];
    const float* ew  = (const float*)d_in[2];
    const float* W1  = (const float*)d_in[3];
    const float* b1  = (const float*)d_in[4];
    const float* g1  = (const float*)d_in[5];
    const float* be1 = (const float*)d_in[6];
    const float* W2  = (const float*)d_in[7];
    const float* b2  = (const float*)d_in[8];
    const float* g2  = (const float*)d_in[9];
    const float* be2 = (const float*)d_in[10];
    const float* Wih = (const float*)d_in[11];
    const float* bih = (const float*)d_in[13];
    const float* bhh = (const float*)d_in[14];
    const float* Wd1 = (const float*)d_in[15];
    const float* bd1 = (const float*)d_in[16];
    const float* Wd2 = (const float*)d_in[17];
    const float* bd2 = (const float*)d_in[18];
    const float* Wd3 = (const float*)d_in[19];
    const float* bd3 = (const float*)d_in[20];
    float* out = (float*)d_out;

    char* w = (char*)d_ws;
    size_t pos = 0;
    auto carve = [&](size_t bytes) -> void* {
        void* p = w + pos;
        pos += (bytes + 255) & ~(size_t)255;
        return p;
    };
    int*   bcursor = (int*)carve(sizeof(int) * 512);
    float* dis     = (float*)carve(sizeof(float) * N_NODES);
    int*   offs    = (int*)carve(sizeof(int) * N_NODES);
    int*   oend    = (int*)carve(sizeof(int) * N_NODES);
    unsigned long long* stage = (unsigned long long*)carve(8 * (size_t)NB * CAP);
    unsigned* csr = (unsigned*)carve(4 * (size_t)NB * CAP);
    unsigned short* xpb  = (unsigned short*)carve(2 * (size_t)N_NODES * DIN);
    unsigned short* xb   = (unsigned short*)carve(2 * (size_t)N_NODES * 32);
    unsigned short* Wg   = (unsigned short*)carve(2 * 768 * 256);
    unsigned short* W2T  = (unsigned short*)carve(2 * 256 * 256);
    unsigned short* Wd1T = (unsigned short*)carve(2 * 256 * 288);
    unsigned short* Wd2T = (unsigned short*)carve(2 * 128 * 256);
    unsigned short* Abf = (unsigned short*)carve(2 * (size_t)N_NODES * H);  // h1p bf16
    unsigned short* Bbf = (unsigned short*)carve(2 * (size_t)N_NODES * H);  // agg2 bf16
    (void)pos; (void)ws_size; (void)in_sizes; (void)n_in; (void)out_size;

    int nbm = (N_NODES + 63) / 64;        // 782
    int nwp = (768 * 256 + 256 * 256 + 256 * 288 + 128 * 256 + N_NODES * 32 + 512 + 255) / 256;

    k_wprep<<<nwp, 256, 0, stream>>>(Wih, W2, Wd1, Wd2, x, Wg, W2T, Wd1T, Wd2T, xb, bcursor);
    k_msplit<<<NTILES, 256, 0, stream>>>(ei, ew, bcursor, stage);
    k_bfin<<<NB, 256, 0, stream>>>(stage, bcursor, x, dis, offs, oend, csr, xpb);
    k_l1<<<N_NODES / RPB, 256, 0, stream>>>(xpb, offs, oend, csr, dis, W1, b1, g1, be1, Abf);
    k_spmm<<<N_NODES / 4, 256, 0, stream>>>(Abf, Bbf, offs, oend, csr, dis);
    k_lgd<<<nbm, 256, 0, stream>>>(Bbf, W2T, b2, g2, be2, Wg, bih, bhh,
                                   Wd1T, bd1, Wd2T, bd2, Wd3, bd3, xb, out);
}